// Round 9
// baseline (291.519 us; speedup 1.0000x reference)
//
#include <hip/hip_runtime.h>

// Problem constants (from reference setup_inputs)
#define B_ 64
#define C_ 256
#define T_ 2048
#define EPS_ 1e-4f
#define NPC ((float)(B_ * T_))   // elements per channel = 131072

#define SPLITS 8
#define BPB (B_ / SPLITS)        // 8 batch rows per stats block
#define T4 (T_ / 4)              // 512 vec4 per row

// Norm kernel tiling: block = 16 channels x 16 t4 (=64 t), 32 batch rows
#define CTILE 16
#define T4TILE 16
#define BCHUNK 32

typedef float f4 __attribute__((ext_vector_type(4)));

// ---------------------------------------------------------------------------
// DIAGNOSTIC ROUND: exact R3-best pair (8-split stats + 16x16 fused norm, NT
// stores), but bntt_norm is dispatched TWICE. norm is idempotent (reads
// x/partials/gamma/beta, writes out), so output is unchanged; the duration
// delta vs the single-dispatch run measures norm's in-situ cost exactly.
// ---------------------------------------------------------------------------

// Kernel 1: per-channel partial sum & sumsq. Grid = C_*SPLITS = 2048 blocks.
__global__ __launch_bounds__(256) void bntt_stats(const float* __restrict__ x,
                                                  float* __restrict__ partials) {
    const int c   = blockIdx.x & (C_ - 1);
    const int s   = blockIdx.x >> 8;
    const int tid = threadIdx.x;

    float sum = 0.0f, sumsq = 0.0f;
    const int b0 = s * BPB;
    #pragma unroll
    for (int b = 0; b < BPB; ++b) {
        const f4* p = (const f4*)(x + (size_t)(b0 + b) * (C_ * T_) + (size_t)c * T_);
        #pragma unroll
        for (int i = 0; i < T4 / 256; ++i) {
            f4 v = p[tid + i * 256];
            sum   += v.x + v.y + v.z + v.w;
            sumsq += v.x * v.x + v.y * v.y + v.z * v.z + v.w * v.w;
        }
    }
    #pragma unroll
    for (int off = 32; off > 0; off >>= 1) {
        sum   += __shfl_down(sum, off);
        sumsq += __shfl_down(sumsq, off);
    }
    __shared__ float ls[4], lss[4];
    const int wave = tid >> 6, lane = tid & 63;
    if (lane == 0) { ls[wave] = sum; lss[wave] = sumsq; }
    __syncthreads();
    if (tid == 0) {
        partials[s * C_ + c]               = ls[0] + ls[1] + ls[2] + ls[3];
        partials[SPLITS * C_ + s * C_ + c] = lss[0] + lss[1] + lss[2] + lss[3];
    }
}

// Kernel 2: finalize + normalize, fused (R3-exact).
__global__ __launch_bounds__(256) void bntt_norm(const float* __restrict__ x,
                                                 const float* __restrict__ gamma,
                                                 const float* __restrict__ beta,
                                                 const float* __restrict__ partials,
                                                 float* __restrict__ out) {
    __shared__ float sg[64][17];   // gamma slice [t_local][c_local], padded
    __shared__ float sb[64][17];   // beta  slice
    __shared__ float smean[CTILE], sistd[CTILE];

    const int tid    = threadIdx.x;
    const int tile   = blockIdx.x & 511;
    const int c0     = (tile >> 5) * CTILE;      // 16 channel-tiles
    const int t4base = (tile & 31) * T4TILE;     // 32 t4-tiles
    const int b0     = (blockIdx.x >> 9) * BCHUNK;

    // finalize stats for this block's 16 channels
    if (tid < CTILE) {
        const int c = c0 + tid;
        float S = 0.0f, SS = 0.0f;
        #pragma unroll
        for (int s = 0; s < SPLITS; ++s) {
            S  += partials[s * C_ + c];
            SS += partials[SPLITS * C_ + s * C_ + c];
        }
        const float mean = S / NPC;
        smean[tid] = mean;
        sistd[tid] = rsqrtf(SS / NPC - mean * mean + EPS_);
    }

    // stage gamma/beta slice: rows t = t4base*4 .. +63, cols c0 .. c0+15
    {
        const int cl  = tid & 15;
        const int tl0 = tid >> 4;                // 0..15
        const int tbase = t4base * 4;
        #pragma unroll
        for (int it = 0; it < 4; ++it) {
            const int tl = tl0 + it * 16;        // 0..63
            const size_t gi = (size_t)(tbase + tl) * C_ + (c0 + cl);
            sg[tl][cl] = gamma[gi];
            sb[tl][cl] = beta[gi];
        }
    }
    __syncthreads();

    // per-thread affine: thread = (ci, t4i)
    const int t4i = tid & 15;
    const int ci  = tid >> 4;
    const float mean = smean[ci];
    const float istd = sistd[ci];
    f4 sc, sh;
    #pragma unroll
    for (int j = 0; j < 4; ++j) {
        const int tl = t4i * 4 + j;
        const float s1 = sg[tl][ci] * istd;
        ((float*)&sc)[j] = s1;
        ((float*)&sh)[j] = fmaf(-mean, s1, sb[tl][ci]);
    }

    // stream 32 batch rows
    size_t idx = ((size_t)b0 * C_ + (c0 + ci)) * T4 + (t4base + t4i);
    const size_t step = (size_t)C_ * T4;         // one batch row
    #pragma unroll 4
    for (int b = 0; b < BCHUNK; ++b) {
        f4 xv = ((const f4*)x)[idx];
        f4 o;
        o.x = fmaf(xv.x, sc.x, sh.x);
        o.y = fmaf(xv.y, sc.y, sh.y);
        o.z = fmaf(xv.z, sc.z, sh.z);
        o.w = fmaf(xv.w, sc.w, sh.w);
        __builtin_nontemporal_store(o, &((f4*)out)[idx]);
        idx += step;
    }
}

extern "C" void kernel_launch(void* const* d_in, const int* in_sizes, int n_in,
                              void* d_out, int out_size, void* d_ws, size_t ws_size,
                              hipStream_t stream) {
    const float* x     = (const float*)d_in[0];
    const float* gamma = (const float*)d_in[1];
    const float* beta  = (const float*)d_in[2];
    float* out = (float*)d_out;
    float* partials = (float*)d_ws;              // 2*SPLITS*C_ = 4096 floats (16 KB)

    bntt_stats<<<C_ * SPLITS, 256, 0, stream>>>(x, partials);

    const int ngrid = (C_ / CTILE) * (T4 / T4TILE) * (B_ / BCHUNK);  // 1024
    // Dispatch norm TWICE (idempotent): dur delta vs single-dispatch baseline
    // = norm's exact in-situ cost. Diagnostic for roofline decision.
    bntt_norm<<<ngrid, 256, 0, stream>>>(x, gamma, beta, partials, out);
    bntt_norm<<<ngrid, 256, 0, stream>>>(x, gamma, beta, partials, out);
}